// Round 2
// baseline (398.240 us; speedup 1.0000x reference)
//
#include <hip/hip_runtime.h>

#define IC 256
#define OC 512
#define NB 32
#define NP 16
#define KTOT 65536   // k = c*256 + i
#define KCH2 256     // k per chunk (kC v2)
#define NKC2 256     // number of k-chunks

// ---------------- Kernel A: h[b][c][p] = relu(b1[c] + sum_i W1[c][i]*x[b][i][p])
// grid: NB*NP blocks, 256 threads (thread = c)
__global__ void kA(const float* __restrict__ x, const float* __restrict__ W1,
                   const float* __restrict__ b1, float* __restrict__ h) {
    int bp = blockIdx.x;
    int b = bp >> 4, p = bp & 15;
    int c = threadIdx.x;
    __shared__ float xs[IC];
    xs[c] = x[b * 4096 + c * 16 + p];
    __syncthreads();
    float acc = b1[c];
    const float* wrow = W1 + c * IC;
    #pragma unroll 8
    for (int i = 0; i < IC; i += 4) {
        float4 w = *(const float4*)(wrow + i);
        acc += w.x * xs[i] + w.y * xs[i + 1] + w.z * xs[i + 2] + w.w * xs[i + 3];
    }
    h[b * 4096 + c * 16 + p] = fmaxf(acc, 0.f);
}

// ---------------- Kernel B: Gt[(i*256+c)*32 + b] = sum_p x[b][i][p]*h[b][c][p]
// also sx[b*256 + i] = sum_p x[b][i][p].  grid: 256 blocks (i = x-channel), 256 threads (c = h-channel)
__global__ void kB(const float* __restrict__ x, const float* __restrict__ h,
                   float* __restrict__ Gt, float* __restrict__ sx) {
    int i = blockIdx.x;
    int c = threadIdx.x;
    __shared__ float xsh[NB * NP];
    for (int e = c; e < NB * NP; e += 256) {
        int b = e >> 4, p = e & 15;
        xsh[e] = x[b * 4096 + i * 16 + p];
    }
    __syncthreads();
    float g[NB];
    const float* hbase = h + c * 16;
    #pragma unroll 8
    for (int b = 0; b < NB; ++b) {
        float4 x0 = *(const float4*)&xsh[b * 16];
        float4 x1 = *(const float4*)&xsh[b * 16 + 4];
        float4 x2 = *(const float4*)&xsh[b * 16 + 8];
        float4 x3 = *(const float4*)&xsh[b * 16 + 12];
        const float* hp = hbase + b * 4096;
        float4 h0 = *(const float4*)(hp);
        float4 h1 = *(const float4*)(hp + 4);
        float4 h2 = *(const float4*)(hp + 8);
        float4 h3 = *(const float4*)(hp + 12);
        g[b] = x0.x * h0.x + x0.y * h0.y + x0.z * h0.z + x0.w * h0.w
             + x1.x * h1.x + x1.y * h1.y + x1.z * h1.z + x1.w * h1.w
             + x2.x * h2.x + x2.y * h2.y + x2.z * h2.z + x2.w * h2.w
             + x3.x * h3.x + x3.y * h3.y + x3.z * h3.z + x3.w * h3.w;
    }
    float* gout = Gt + (size_t)i * 8192 + (size_t)c * 32;
    #pragma unroll
    for (int j = 0; j < 8; ++j) {
        float4 v = make_float4(g[j * 4], g[j * 4 + 1], g[j * 4 + 2], g[j * 4 + 3]);
        *(float4*)(gout + j * 4) = v;
    }
    if (c < NB) {
        float s = 0.f;
        #pragma unroll
        for (int p = 0; p < 16; ++p) s += xsh[c * 16 + p];
        sx[c * IC + i] = s;
    }
}

// ---------------- Kernel C v2: partial[kc][b][o] = sum_{k in chunk} W2[o][k] * Gt[k][b]
// W2 has ZERO inter-block reuse -> stream global->VGPR exactly once (no LDS round-trip).
// Gt chunk (256 k x 32 b = 32 KB) staged ONCE per block into LDS (8 passes of 256 float4),
// stride 36 (16B-aligned; j-phase read collisions are 2-way = free per m136).
// Thread = (j = k-phase 0..3, r = row-group 0..63); owns 4 rows x 32 b, k = j*4+t per 16-k step.
// j-split makes w-loads 16 rows x 64B contiguous per wave-instr (16 lines, not 64).
// Each ds_read_b128 of g feeds 16 FMAs.
// Epilogue: width-4 shfl_xor butterfly merges the 4 k-phases (all lanes end with full sums);
// stores use COMPILE-TIME acc indices + exec-mask on j (rule #20: no runtime-indexed arrays).
// grid: (NKC2, 2) = 512 blocks (2/CU), 256 threads. acc 128 VGPR -> launch_bounds(256,2).
__global__ __launch_bounds__(256, 2)
void kC(const float* __restrict__ W2, const float* __restrict__ Gt,
        float* __restrict__ partial) {
    __shared__ __align__(16) float gsh[KCH2 * 36];
    const int kc = blockIdx.x;            // 0..255 k-chunk
    const int ob = blockIdx.y;            // 0..1  o-half
    const int tid = threadIdx.x;
    const int j = tid & 3;                // k-phase within 16-k step
    const int r = tid >> 2;               // 0..63 row group
    const int j4 = j * 4;
    const int k0 = kc * KCH2;

    // one-shot stage: Gt slab [256 k][32 b] = 2048 float4 -> gsh[k*36 + b]
    {
        const float* gsrc = Gt + (size_t)k0 * 32;
        #pragma unroll
        for (int c = 0; c < 8; ++c) {
            int f = tid + c * 256;                      // float4 index, 0..2047
            float4 v = *(const float4*)(gsrc + (size_t)f * 4);
            *(float4*)&gsh[(f >> 3) * 36 + (f & 7) * 4] = v;
        }
    }
    __syncthreads();

    const size_t orow = (size_t)(ob * 256 + r);
    const float* w0 = W2 + (orow      ) * KTOT + k0 + j4;
    const float* w1 = W2 + (orow +  64) * KTOT + k0 + j4;
    const float* w2r= W2 + (orow + 128) * KTOT + k0 + j4;
    const float* w3 = W2 + (orow + 192) * KTOT + k0 + j4;

    float acc[4][32];
    #pragma unroll
    for (int rr = 0; rr < 4; ++rr)
        #pragma unroll
        for (int b = 0; b < 32; ++b) acc[rr][b] = 0.f;

    auto body = [&](const float4 (&wv)[4], int kkv) {
        const int kb = (kkv + j4) * 36;
        #pragma unroll
        for (int t = 0; t < 4; ++t) {
            float4 gv[8];
            #pragma unroll
            for (int bq = 0; bq < 8; ++bq)
                gv[bq] = *(const float4*)&gsh[kb + t * 36 + bq * 4];
            #pragma unroll
            for (int rr = 0; rr < 4; ++rr) {
                float wt = (t == 0) ? wv[rr].x : (t == 1) ? wv[rr].y
                         : (t == 2) ? wv[rr].z : wv[rr].w;
                #pragma unroll
                for (int bq = 0; bq < 8; ++bq) {
                    acc[rr][bq * 4 + 0] = fmaf(wt, gv[bq].x, acc[rr][bq * 4 + 0]);
                    acc[rr][bq * 4 + 1] = fmaf(wt, gv[bq].y, acc[rr][bq * 4 + 1]);
                    acc[rr][bq * 4 + 2] = fmaf(wt, gv[bq].z, acc[rr][bq * 4 + 2]);
                    acc[rr][bq * 4 + 3] = fmaf(wt, gv[bq].w, acc[rr][bq * 4 + 3]);
                }
            }
        }
    };

    // double-buffered w stream: load one 16-k step ahead to hide HBM latency
    float4 wa[4], wb[4];
    wa[0] = *(const float4*)(w0);  wa[1] = *(const float4*)(w1);
    wa[2] = *(const float4*)(w2r); wa[3] = *(const float4*)(w3);

    for (int kk = 0; kk < KCH2; kk += 32) {
        wb[0] = *(const float4*)(w0 + kk + 16);
        wb[1] = *(const float4*)(w1 + kk + 16);
        wb[2] = *(const float4*)(w2r + kk + 16);
        wb[3] = *(const float4*)(w3 + kk + 16);
        body(wa, kk);
        if (kk + 32 < KCH2) {
            wa[0] = *(const float4*)(w0 + kk + 32);
            wa[1] = *(const float4*)(w1 + kk + 32);
            wa[2] = *(const float4*)(w2r + kk + 32);
            wa[3] = *(const float4*)(w3 + kk + 32);
        }
        body(wb, kk + 16);
    }

    // merge the 4 k-phase partials within each 4-lane group (width-4 butterfly);
    // afterwards ALL lanes hold the full-k sum for every b
    #pragma unroll
    for (int rr = 0; rr < 4; ++rr)
        #pragma unroll
        for (int b = 0; b < 32; ++b) {
            acc[rr][b] += __shfl_xor(acc[rr][b], 1, 64);
            acc[rr][b] += __shfl_xor(acc[rr][b], 2, 64);
        }

    // write: lane j covers b = j*8..j*8+7. b is COMPILE-TIME (unrolled), j only
    // appears in the predicate -> acc stays in registers (no scratch).
    float* pout = partial + (size_t)kc * 16384 + ob * 256 + r;
    #pragma unroll
    for (int rr = 0; rr < 4; ++rr)
        #pragma unroll
        for (int b = 0; b < 32; ++b)
            if ((b >> 3) == j)
                pout[(size_t)b * 512 + rr * 64] = acc[rr][b];
}

// ---------------- kBias: bias[b][o] = sum_i b2[o*256+i]*sx[b*256+i]
// grid: 64 blocks (8 o each), 256 threads (32b x 8o)
__global__ void kBias(const float* __restrict__ b2, const float* __restrict__ sx,
                      float* __restrict__ bias) {
    __shared__ float sxs[32 * 260];   // stride 260 breaks 256-stride bank aliasing
    __shared__ float b2s[8 * 260];
    int tid = threadIdx.x;
    int o0 = blockIdx.x * 8;
    #pragma unroll
    for (int p = 0; p < 32; ++p) {
        int f = tid + p * 256;
        sxs[(f >> 8) * 260 + (f & 255)] = sx[f];
    }
    #pragma unroll
    for (int p = 0; p < 8; ++p) {
        int f = tid + p * 256;
        b2s[(f >> 8) * 260 + (f & 255)] = b2[(size_t)o0 * 256 + f];
    }
    __syncthreads();
    int b = tid >> 3, ol = tid & 7;
    float acc = 0.f;
    #pragma unroll 8
    for (int i = 0; i < 256; i += 4) {
        float4 sv = *(float4*)&sxs[b * 260 + i];
        float4 wv = *(float4*)&b2s[ol * 260 + i];
        acc += sv.x * wv.x + sv.y * wv.y + sv.z * wv.z + sv.w * wv.w;
    }
    bias[b * 512 + o0 + ol] = acc;
}

// ---------------- kRed: out[j] = sum_{kc<256} partial[kc][j] + bias[j]
// grid: 256 blocks (64 j each), 256 threads = 4 kc-groups x 64 j
__global__ void kRed(const float* __restrict__ partial, const float* __restrict__ bias,
                     float* __restrict__ out) {
    __shared__ float red[256];
    int tid = threadIdx.x;
    int q = tid >> 6, jj = tid & 63;
    int j = blockIdx.x * 64 + jj;
    float s = 0.f;
    #pragma unroll 8
    for (int t = 0; t < 64; ++t)
        s += partial[(size_t)(q * 64 + t) * 16384 + j];
    red[tid] = s;
    __syncthreads();
    if (tid < 64)
        out[j] = red[jj] + red[64 + jj] + red[128 + jj] + red[192 + jj] + bias[j];
}

extern "C" void kernel_launch(void* const* d_in, const int* in_sizes, int n_in,
                              void* d_out, int out_size, void* d_ws, size_t ws_size,
                              hipStream_t stream) {
    const float* x  = (const float*)d_in[0];
    const float* W1 = (const float*)d_in[1];
    const float* b1 = (const float*)d_in[2];
    const float* W2 = (const float*)d_in[3];
    const float* b2 = (const float*)d_in[4];
    // d_in[5] (Wa), d_in[6] (ba): dead code in the reference — unused.
    float* out = (float*)d_out;
    float* ws = (float*)d_ws;

    // ws layout (floats) — total 6,430,720 fl = 25.7 MB
    float* h       = ws;                 // 131072; dead after kB -> reused as bias
    float* sx      = ws + 131072;        // 8192
    float* Gt      = ws + 139264;        // 2097152  [k][b]
    float* partial = ws + 2236416;       // NKC2 * 16384 = 4194304
    float* bias    = ws;                 // aliases h (dead by the time kBias runs)

    kA<<<NB * NP, 256, 0, stream>>>(x, W1, b1, h);
    kB<<<IC, 256, 0, stream>>>(x, h, Gt, sx);
    kBias<<<64, 256, 0, stream>>>(b2, sx, bias);
    kC<<<dim3(NKC2, 2), 256, 0, stream>>>(W2, Gt, partial);
    kRed<<<256, 256, 0, stream>>>(partial, bias, out);
}

// Round 3
// 372.965 us; speedup vs baseline: 1.0678x; 1.0678x over previous
//
#include <hip/hip_runtime.h>

#define IC 256
#define OC 512
#define NB 32
#define NP 16
#define KTOT 65536   // k = c*256 + i
#define KCH2 256     // k per chunk (kC v3)
#define NKC2 256     // number of k-chunks

// ---------------- Kernel A: h[b][c][p] = relu(b1[c] + sum_i W1[c][i]*x[b][i][p])
// grid: NB*NP blocks, 256 threads (thread = c)
__global__ void kA(const float* __restrict__ x, const float* __restrict__ W1,
                   const float* __restrict__ b1, float* __restrict__ h) {
    int bp = blockIdx.x;
    int b = bp >> 4, p = bp & 15;
    int c = threadIdx.x;
    __shared__ float xs[IC];
    xs[c] = x[b * 4096 + c * 16 + p];
    __syncthreads();
    float acc = b1[c];
    const float* wrow = W1 + c * IC;
    #pragma unroll 8
    for (int i = 0; i < IC; i += 4) {
        float4 w = *(const float4*)(wrow + i);
        acc += w.x * xs[i] + w.y * xs[i + 1] + w.z * xs[i + 2] + w.w * xs[i + 3];
    }
    h[b * 4096 + c * 16 + p] = fmaxf(acc, 0.f);
}

// ---------------- Kernel B: Gt[(i*256+c)*32 + b] = sum_p x[b][i][p]*h[b][c][p]
// also sx[b*256 + i] = sum_p x[b][i][p].  grid: 256 blocks (i = x-channel), 256 threads (c = h-channel)
__global__ void kB(const float* __restrict__ x, const float* __restrict__ h,
                   float* __restrict__ Gt, float* __restrict__ sx) {
    int i = blockIdx.x;
    int c = threadIdx.x;
    __shared__ float xsh[NB * NP];
    for (int e = c; e < NB * NP; e += 256) {
        int b = e >> 4, p = e & 15;
        xsh[e] = x[b * 4096 + i * 16 + p];
    }
    __syncthreads();
    float g[NB];
    const float* hbase = h + c * 16;
    #pragma unroll 8
    for (int b = 0; b < NB; ++b) {
        float4 x0 = *(const float4*)&xsh[b * 16];
        float4 x1 = *(const float4*)&xsh[b * 16 + 4];
        float4 x2 = *(const float4*)&xsh[b * 16 + 8];
        float4 x3 = *(const float4*)&xsh[b * 16 + 12];
        const float* hp = hbase + b * 4096;
        float4 h0 = *(const float4*)(hp);
        float4 h1 = *(const float4*)(hp + 4);
        float4 h2 = *(const float4*)(hp + 8);
        float4 h3 = *(const float4*)(hp + 12);
        g[b] = x0.x * h0.x + x0.y * h0.y + x0.z * h0.z + x0.w * h0.w
             + x1.x * h1.x + x1.y * h1.y + x1.z * h1.z + x1.w * h1.w
             + x2.x * h2.x + x2.y * h2.y + x2.z * h2.z + x2.w * h2.w
             + x3.x * h3.x + x3.y * h3.y + x3.z * h3.z + x3.w * h3.w;
    }
    float* gout = Gt + (size_t)i * 8192 + (size_t)c * 32;
    #pragma unroll
    for (int j = 0; j < 8; ++j) {
        float4 v = make_float4(g[j * 4], g[j * 4 + 1], g[j * 4 + 2], g[j * 4 + 3]);
        *(float4*)(gout + j * 4) = v;
    }
    if (c < NB) {
        float s = 0.f;
        #pragma unroll
        for (int p = 0; p < 16; ++p) s += xsh[c * 16 + p];
        sx[c * IC + i] = s;
    }
}

// ---------------- Kernel C v3: partial[kc][b][o] = sum_{k in chunk} W2[o][k] * Gt[k][b]
// Restructured after the v2 spill disaster (VGPR_Count=128, 220 MB scratch traffic):
//  - thread = ONE o-row -> acc[32] = 32 VGPRs only. No LDS, no barrier, no butterfly.
//  - W2[row][kk..kk+15] per lane = one aligned 64B line per 16-k step; W2 streamed
//    exactly once (134 MB = the HBM floor for this GEMM).
//  - Gt index is independent of threadIdx -> wave-uniform -> compiler emits s_load
//    (scalar cache / lgkm pipe); FMAs are v_fmac(vacc, s_g, v_w) -> zero LDS, zero
//    VMEM for g.
//  - explicit 2-deep w double-buffer (static ping-pong, no runtime-indexed arrays).
// grid: (NKC2, 2) = 512 blocks (2/CU), 256 threads.
__global__ __launch_bounds__(256)
void kC(const float* __restrict__ W2, const float* __restrict__ Gt,
        float* __restrict__ partial) {
    const int kc = blockIdx.x;            // 0..255 k-chunk
    const int ob = blockIdx.y;            // 0..1  o-half
    const int tid = threadIdx.x;
    const int k0 = kc * KCH2;
    const int orow = ob * 256 + tid;

    const float* wrow = W2 + (size_t)orow * KTOT + k0;
    const float* gch  = Gt + (size_t)k0 * 32;      // wave-uniform base

    float acc[NB];
    #pragma unroll
    for (int b = 0; b < NB; ++b) acc[b] = 0.f;

    // body: 16 k-steps using one 64B w-line held in wv[0..3]
    auto body = [&](const float4 (&wv)[4], int base) {
        #pragma unroll
        for (int q = 0; q < 4; ++q) {
            #pragma unroll
            for (int t = 0; t < 4; ++t) {
                const float wt = (t == 0) ? wv[q].x : (t == 1) ? wv[q].y
                               : (t == 2) ? wv[q].z : wv[q].w;
                const float* gk = gch + (size_t)(base + q * 4 + t) * 32;  // uniform
                #pragma unroll
                for (int b = 0; b < NB; ++b)
                    acc[b] = fmaf(wt, gk[b], acc[b]);
            }
        }
    };

    float4 wa[4], wb[4];
    #pragma unroll
    for (int q = 0; q < 4; ++q) wa[q] = *(const float4*)(wrow + q * 4);

    for (int kk = 0; kk < KCH2; kk += 32) {
        #pragma unroll
        for (int q = 0; q < 4; ++q)
            wb[q] = *(const float4*)(wrow + kk + 16 + q * 4);
        body(wa, kk);
        if (kk + 32 < KCH2) {
            #pragma unroll
            for (int q = 0; q < 4; ++q)
                wa[q] = *(const float4*)(wrow + kk + 32 + q * 4);
        }
        body(wb, kk + 16);
    }

    // write: 32 stores, each wave = 256B contiguous (64 lanes x consecutive o)
    float* pout = partial + (size_t)kc * 16384 + orow;
    #pragma unroll
    for (int b = 0; b < NB; ++b)
        pout[(size_t)b * 512] = acc[b];
}

// ---------------- kBias: bias[b][o] = sum_i b2[o*256+i]*sx[b*256+i]
// grid: 64 blocks (8 o each), 256 threads (32b x 8o)
__global__ void kBias(const float* __restrict__ b2, const float* __restrict__ sx,
                      float* __restrict__ bias) {
    __shared__ float sxs[32 * 260];   // stride 260 breaks 256-stride bank aliasing
    __shared__ float b2s[8 * 260];
    int tid = threadIdx.x;
    int o0 = blockIdx.x * 8;
    #pragma unroll
    for (int p = 0; p < 32; ++p) {
        int f = tid + p * 256;
        sxs[(f >> 8) * 260 + (f & 255)] = sx[f];
    }
    #pragma unroll
    for (int p = 0; p < 8; ++p) {
        int f = tid + p * 256;
        b2s[(f >> 8) * 260 + (f & 255)] = b2[(size_t)o0 * 256 + f];
    }
    __syncthreads();
    int b = tid >> 3, ol = tid & 7;
    float acc = 0.f;
    #pragma unroll 8
    for (int i = 0; i < 256; i += 4) {
        float4 sv = *(float4*)&sxs[b * 260 + i];
        float4 wv = *(float4*)&b2s[ol * 260 + i];
        acc += sv.x * wv.x + sv.y * wv.y + sv.z * wv.z + sv.w * wv.w;
    }
    bias[b * 512 + o0 + ol] = acc;
}

// ---------------- kRed: out[j] = sum_{kc<256} partial[kc][j] + bias[j]
// grid: 256 blocks (64 j each), 256 threads = 4 kc-groups x 64 j
__global__ void kRed(const float* __restrict__ partial, const float* __restrict__ bias,
                     float* __restrict__ out) {
    __shared__ float red[256];
    int tid = threadIdx.x;
    int q = tid >> 6, jj = tid & 63;
    int j = blockIdx.x * 64 + jj;
    float s = 0.f;
    #pragma unroll 8
    for (int t = 0; t < 64; ++t)
        s += partial[(size_t)(q * 64 + t) * 16384 + j];
    red[tid] = s;
    __syncthreads();
    if (tid < 64)
        out[j] = red[jj] + red[64 + jj] + red[128 + jj] + red[192 + jj] + bias[j];
}

extern "C" void kernel_launch(void* const* d_in, const int* in_sizes, int n_in,
                              void* d_out, int out_size, void* d_ws, size_t ws_size,
                              hipStream_t stream) {
    const float* x  = (const float*)d_in[0];
    const float* W1 = (const float*)d_in[1];
    const float* b1 = (const float*)d_in[2];
    const float* W2 = (const float*)d_in[3];
    const float* b2 = (const float*)d_in[4];
    // d_in[5] (Wa), d_in[6] (ba): dead code in the reference — unused.
    float* out = (float*)d_out;
    float* ws = (float*)d_ws;

    // ws layout (floats) — total 6,430,720 fl = 25.7 MB
    float* h       = ws;                 // 131072; dead after kB -> reused as bias
    float* sx      = ws + 131072;        // 8192
    float* Gt      = ws + 139264;        // 2097152  [k][b]
    float* partial = ws + 2236416;       // NKC2 * 16384 = 4194304
    float* bias    = ws;                 // aliases h (dead by the time kBias runs)

    kA<<<NB * NP, 256, 0, stream>>>(x, W1, b1, h);
    kB<<<IC, 256, 0, stream>>>(x, h, Gt, sx);
    kBias<<<64, 256, 0, stream>>>(b2, sx, bias);
    kC<<<dim3(NKC2, 2), 256, 0, stream>>>(W2, Gt, partial);
    kRed<<<256, 256, 0, stream>>>(partial, bias, out);
}

// Round 4
// 363.741 us; speedup vs baseline: 1.0948x; 1.0254x over previous
//
#include <hip/hip_runtime.h>

#define IC 256
#define OC 512
#define NB 32
#define NP 16
#define KTOT 65536   // k = c*256 + i
#define KCH2 64      // k per chunk (kC v4: small chunks -> 2048 blocks -> 8 blocks/CU)
#define NKC2 1024    // number of k-chunks

// ---------------- Kernel A: h[b][c][p] = relu(b1[c] + sum_i W1[c][i]*x[b][i][p])
// grid: NB*NP blocks, 256 threads (thread = c)
__global__ void kA(const float* __restrict__ x, const float* __restrict__ W1,
                   const float* __restrict__ b1, float* __restrict__ h) {
    int bp = blockIdx.x;
    int b = bp >> 4, p = bp & 15;
    int c = threadIdx.x;
    __shared__ float xs[IC];
    xs[c] = x[b * 4096 + c * 16 + p];
    __syncthreads();
    float acc = b1[c];
    const float* wrow = W1 + c * IC;
    #pragma unroll 8
    for (int i = 0; i < IC; i += 4) {
        float4 w = *(const float4*)(wrow + i);
        acc += w.x * xs[i] + w.y * xs[i + 1] + w.z * xs[i + 2] + w.w * xs[i + 3];
    }
    h[b * 4096 + c * 16 + p] = fmaxf(acc, 0.f);
}

// ---------------- Kernel B: Gt[(i*256+c)*32 + b] = sum_p x[b][i][p]*h[b][c][p]
// also sx[b*256 + i] = sum_p x[b][i][p].  grid: 256 blocks (i = x-channel), 256 threads (c = h-channel)
__global__ void kB(const float* __restrict__ x, const float* __restrict__ h,
                   float* __restrict__ Gt, float* __restrict__ sx) {
    int i = blockIdx.x;
    int c = threadIdx.x;
    __shared__ float xsh[NB * NP];
    for (int e = c; e < NB * NP; e += 256) {
        int b = e >> 4, p = e & 15;
        xsh[e] = x[b * 4096 + i * 16 + p];
    }
    __syncthreads();
    float g[NB];
    const float* hbase = h + c * 16;
    #pragma unroll 8
    for (int b = 0; b < NB; ++b) {
        float4 x0 = *(const float4*)&xsh[b * 16];
        float4 x1 = *(const float4*)&xsh[b * 16 + 4];
        float4 x2 = *(const float4*)&xsh[b * 16 + 8];
        float4 x3 = *(const float4*)&xsh[b * 16 + 12];
        const float* hp = hbase + b * 4096;
        float4 h0 = *(const float4*)(hp);
        float4 h1 = *(const float4*)(hp + 4);
        float4 h2 = *(const float4*)(hp + 8);
        float4 h3 = *(const float4*)(hp + 12);
        g[b] = x0.x * h0.x + x0.y * h0.y + x0.z * h0.z + x0.w * h0.w
             + x1.x * h1.x + x1.y * h1.y + x1.z * h1.z + x1.w * h1.w
             + x2.x * h2.x + x2.y * h2.y + x2.z * h2.z + x2.w * h2.w
             + x3.x * h3.x + x3.y * h3.y + x3.z * h3.z + x3.w * h3.w;
    }
    float* gout = Gt + (size_t)i * 8192 + (size_t)c * 32;
    #pragma unroll
    for (int j = 0; j < 8; ++j) {
        float4 v = make_float4(g[j * 4], g[j * 4 + 1], g[j * 4 + 2], g[j * 4 + 3]);
        *(float4*)(gout + j * 4) = v;
    }
    if (c < NB) {
        float s = 0.f;
        #pragma unroll
        for (int p = 0; p < 16; ++p) s += xsh[c * 16 + p];
        sx[c * IC + i] = s;
    }
}

// ---------------- Kernel C v4: partial[kc][b][o] = sum_{k in chunk} W2[o][k] * Gt[k][b]
// v3 post-mortem: traffic at floor (FETCH 140MB, WRITE 16MB) but dur 124us at 16% HBM,
// VALUBusy 36.6%, Occupancy 21% -> STALL-BOUND on s_load (scalar g operands) with only
// 8 waves/CU to hide the latency. v4: same per-thread structure (thread = one o-row,
// acc[32] = 32 VGPR, W2 streamed once per lane as 64B lines, Gt wave-uniform -> s_load),
// but 4x the blocks: KCH2=64, grid (1024,2) = 2048 blocks ~ 8 blocks/CU ~ 28-32 waves/CU.
// Stall fraction shrinks ~linearly with resident waves.
__global__ __launch_bounds__(256)
void kC(const float* __restrict__ W2, const float* __restrict__ Gt,
        float* __restrict__ partial) {
    const int kc = blockIdx.x;            // 0..1023 k-chunk
    const int ob = blockIdx.y;            // 0..1   o-half
    const int tid = threadIdx.x;
    const int k0 = kc * KCH2;
    const int orow = ob * 256 + tid;

    const float* wrow = W2 + (size_t)orow * KTOT + k0;
    const float* gch  = Gt + (size_t)k0 * 32;      // wave-uniform base

    float acc[NB];
    #pragma unroll
    for (int b = 0; b < NB; ++b) acc[b] = 0.f;

    // body: 16 k-steps using one 64B w-line held in wv[0..3]
    auto body = [&](const float4 (&wv)[4], int base) {
        #pragma unroll
        for (int q = 0; q < 4; ++q) {
            #pragma unroll
            for (int t = 0; t < 4; ++t) {
                const float wt = (t == 0) ? wv[q].x : (t == 1) ? wv[q].y
                               : (t == 2) ? wv[q].z : wv[q].w;
                const float* gk = gch + (size_t)(base + q * 4 + t) * 32;  // uniform
                #pragma unroll
                for (int b = 0; b < NB; ++b)
                    acc[b] = fmaf(wt, gk[b], acc[b]);
            }
        }
    };

    float4 wa[4], wb[4];
    #pragma unroll
    for (int q = 0; q < 4; ++q) wa[q] = *(const float4*)(wrow + q * 4);

    for (int kk = 0; kk < KCH2; kk += 32) {
        #pragma unroll
        for (int q = 0; q < 4; ++q)
            wb[q] = *(const float4*)(wrow + kk + 16 + q * 4);
        body(wa, kk);
        if (kk + 32 < KCH2) {
            #pragma unroll
            for (int q = 0; q < 4; ++q)
                wa[q] = *(const float4*)(wrow + kk + 32 + q * 4);
        }
        body(wb, kk + 16);
    }

    // write: 32 stores, each wave = 256B contiguous (64 lanes x consecutive o)
    float* pout = partial + (size_t)kc * 16384 + orow;
    #pragma unroll
    for (int b = 0; b < NB; ++b)
        pout[(size_t)b * 512] = acc[b];
}

// ---------------- kBias: bias[b][o] = sum_i b2[o*256+i]*sx[b*256+i]
// grid: 64 blocks (8 o each), 256 threads (32b x 8o)
__global__ void kBias(const float* __restrict__ b2, const float* __restrict__ sx,
                      float* __restrict__ bias) {
    __shared__ float sxs[32 * 260];   // stride 260 breaks 256-stride bank aliasing
    __shared__ float b2s[8 * 260];
    int tid = threadIdx.x;
    int o0 = blockIdx.x * 8;
    #pragma unroll
    for (int p = 0; p < 32; ++p) {
        int f = tid + p * 256;
        sxs[(f >> 8) * 260 + (f & 255)] = sx[f];
    }
    #pragma unroll
    for (int p = 0; p < 8; ++p) {
        int f = tid + p * 256;
        b2s[(f >> 8) * 260 + (f & 255)] = b2[(size_t)o0 * 256 + f];
    }
    __syncthreads();
    int b = tid >> 3, ol = tid & 7;
    float acc = 0.f;
    #pragma unroll 8
    for (int i = 0; i < 256; i += 4) {
        float4 sv = *(float4*)&sxs[b * 260 + i];
        float4 wv = *(float4*)&b2s[ol * 260 + i];
        acc += sv.x * wv.x + sv.y * wv.y + sv.z * wv.z + sv.w * wv.w;
    }
    bias[b * 512 + o0 + ol] = acc;
}

// ---------------- kRed: out[j] = sum_{kc<1024} partial[kc][j] + bias[j]
// grid: 256 blocks (64 j each), 256 threads = 4 kc-groups x 64 j (256 slabs each)
__global__ void kRed(const float* __restrict__ partial, const float* __restrict__ bias,
                     float* __restrict__ out) {
    __shared__ float red[256];
    int tid = threadIdx.x;
    int q = tid >> 6, jj = tid & 63;
    int j = blockIdx.x * 64 + jj;
    float s = 0.f;
    #pragma unroll 8
    for (int t = 0; t < 256; ++t)
        s += partial[(size_t)(q * 256 + t) * 16384 + j];
    red[tid] = s;
    __syncthreads();
    if (tid < 64)
        out[j] = red[jj] + red[64 + jj] + red[128 + jj] + red[192 + jj] + bias[j];
}

extern "C" void kernel_launch(void* const* d_in, const int* in_sizes, int n_in,
                              void* d_out, int out_size, void* d_ws, size_t ws_size,
                              hipStream_t stream) {
    const float* x  = (const float*)d_in[0];
    const float* W1 = (const float*)d_in[1];
    const float* b1 = (const float*)d_in[2];
    const float* W2 = (const float*)d_in[3];
    const float* b2 = (const float*)d_in[4];
    // d_in[5] (Wa), d_in[6] (ba): dead code in the reference — unused.
    float* out = (float*)d_out;
    float* ws = (float*)d_ws;

    // ws layout (floats) — total 19,013,632 fl = 76.1 MB
    float* h       = ws;                 // 131072; dead after kB -> reused as bias
    float* sx      = ws + 131072;        // 8192
    float* Gt      = ws + 139264;        // 2097152  [k][b]
    float* partial = ws + 2236416;       // NKC2 * 16384 = 16777216
    float* bias    = ws;                 // aliases h (dead by the time kBias runs)

    kA<<<NB * NP, 256, 0, stream>>>(x, W1, b1, h);
    kB<<<IC, 256, 0, stream>>>(x, h, Gt, sx);
    kBias<<<64, 256, 0, stream>>>(b2, sx, bias);
    kC<<<dim3(NKC2, 2), 256, 0, stream>>>(W2, Gt, partial);
    kRed<<<256, 256, 0, stream>>>(partial, bias, out);
}